// Round 1
// baseline (7410.842 us; speedup 1.0000x reference)
//
#include <hip/hip_runtime.h>
#include <math.h>

constexpr int cB = 32, cCIN = 16, cT = 4096, cH = 192, cD = 4, cE = 4, cK = 7;
constexpr int cBANDS = 16, cP = 8, cHM = 384, cNCLS = 50, cBINS = 2049;
constexpr float cEPS = 1e-5f;
constexpr int TT = 64, HALO = 24;          // block1/block2 time tile, dwconv halo (3*8)
constexpr float INV_SQRT2 = 0.7071067811865475f;

__device__ __forceinline__ float gelu_exact(float v) {
    return 0.5f * v * (1.0f + erff(v * INV_SQRT2));
}

// ---------------- zero scratch ----------------
__global__ __launch_bounds__(256) void k_zero(float* __restrict__ p, int n) {
    int i = blockIdx.x * 256 + threadIdx.x;
    if (i < n) p[i] = 0.f;
}

// ---------------- FFT magnitude: one block per (b, cin) ----------------
__global__ __launch_bounds__(256) void k_fft_mag(const float* __restrict__ x,
                                                 float* __restrict__ mag) {
    __shared__ float Sr[2][cT];
    __shared__ float Si[2][cT];
    int b = blockIdx.x / cCIN, c = blockIdx.x % cCIN;
    const float* xp = x + ((size_t)b * cCIN + c) * cT;
    for (int t = threadIdx.x; t < cT; t += 256) { Sr[0][t] = xp[t]; Si[0][t] = 0.f; }
    __syncthreads();
    int cur = 0, n = cT, ls = 0;
    while (n > 1) {
        int m = n >> 1;
        int s = 1 << ls;
        float theta0 = -6.283185307179586f / (float)n;
        for (int j = threadIdx.x; j < cT / 2; j += 256) {
            int p = j >> ls;
            float ang = theta0 * (float)p;
            float wi, wr;
            sincosf(ang, &wi, &wr);          // wr=cos, wi=-sin(2*pi*p/n)
            int ia = j, ib = j + cT / 2;
            float ar = Sr[cur][ia], ai = Si[cur][ia];
            float br = Sr[cur][ib], bi = Si[cur][ib];
            int oa = j + (j & ~(s - 1));
            int ob = oa + s;
            Sr[cur ^ 1][oa] = ar + br;
            Si[cur ^ 1][oa] = ai + bi;
            float tr = ar - br, ti = ai - bi;
            Sr[cur ^ 1][ob] = tr * wr - ti * wi;
            Si[cur ^ 1][ob] = tr * wi + ti * wr;
        }
        __syncthreads();
        cur ^= 1; n = m; ls += 1;
    }
    const float scale = (1.0f / 64.0f) * (1.0f / 16.0f); // ortho norm, mean over CIN
    for (int k = threadIdx.x; k < cBINS; k += 256) {
        float re = Sr[cur][k], im = Si[cur][k];
        atomicAdd(&mag[b * cBINS + k], sqrtf(re * re + im * im) * scale);
    }
}

// ---------------- RBF basis (normalized rows) ----------------
__global__ __launch_bounds__(256) void k_basis(float* __restrict__ basis) {
    __shared__ float vals[cBINS];
    __shared__ float red[256];
    int band = blockIdx.x;
    float cb = (float)band / 15.0f;
    float inv_w = 15.0f / 1.5f;          // 1/width, width = 1.5/(bands-1)
    float local = 0.f;
    for (int k = threadIdx.x; k < cBINS; k += 256) {
        float f = (float)k / 2048.0f;
        float u = (f - cb) * inv_w;
        float v = expf(-0.5f * u * u);
        vals[k] = v;
        local += v;
    }
    red[threadIdx.x] = local;
    __syncthreads();
    for (int s = 128; s > 0; s >>= 1) {
        if (threadIdx.x < s) red[threadIdx.x] += red[threadIdx.x + s];
        __syncthreads();
    }
    float inv_sum = 1.0f / fmaxf(red[0], 1e-8f);
    for (int k = threadIdx.x; k < cBINS; k += 256)
        basis[band * cBINS + k] = vals[k] * inv_sum;
}

// ---------------- summary = log1p(mag) @ basis.T ----------------
__global__ __launch_bounds__(256) void k_summary(const float* __restrict__ mag,
                                                 const float* __restrict__ basis,
                                                 float* __restrict__ summary) {
    int b = blockIdx.x;
    float acc[cBANDS];
#pragma unroll
    for (int i = 0; i < cBANDS; i++) acc[i] = 0.f;
    for (int k = threadIdx.x; k < cBINS; k += 256) {
        float lm = log1pf(mag[b * cBINS + k]);
#pragma unroll
        for (int band = 0; band < cBANDS; band++) acc[band] += lm * basis[band * cBINS + k];
    }
    __shared__ float red[cBANDS][256];
#pragma unroll
    for (int band = 0; band < cBANDS; band++) red[band][threadIdx.x] = acc[band];
    __syncthreads();
    for (int s = 128; s > 0; s >>= 1) {
        if (threadIdx.x < s)
#pragma unroll
            for (int band = 0; band < cBANDS; band++)
                red[band][threadIdx.x] += red[band][threadIdx.x + s];
        __syncthreads();
    }
    if (threadIdx.x < cBANDS) summary[b * cBANDS + threadIdx.x] = red[threadIdx.x][0];
}

// ---------------- router: LN, proj, prototypes, softmax, routes+gains ----------------
__global__ __launch_bounds__(64) void k_router(
    const float* __restrict__ summary, const float* __restrict__ ln_g,
    const float* __restrict__ ln_b, const float* __restrict__ proj_w,
    const float* __restrict__ prototypes, const float* __restrict__ route_lib,
    const float* __restrict__ gain_lib, float* __restrict__ routes,
    float* __restrict__ gains) {
    int b = threadIdx.x;
    if (b >= cB) return;
    float s[cBANDS];
    float mean = 0.f;
#pragma unroll
    for (int i = 0; i < cBANDS; i++) { s[i] = summary[b * cBANDS + i]; mean += s[i]; }
    mean *= (1.0f / cBANDS);
    float var = 0.f;
#pragma unroll
    for (int i = 0; i < cBANDS; i++) { float d = s[i] - mean; var += d * d; }
    var *= (1.0f / cBANDS);
    float rstd = rsqrtf(var + cEPS);
#pragma unroll
    for (int i = 0; i < cBANDS; i++) s[i] = (s[i] - mean) * rstd * ln_g[i] + ln_b[i];
    float rs[cBANDS];
#pragma unroll
    for (int j = 0; j < cBANDS; j++) {
        float a = 0.f;
#pragma unroll
        for (int i = 0; i < cBANDS; i++) a += s[i] * proj_w[j * cBANDS + i];
        rs[j] = a;
    }
    float logits[cP];
    float mx = -1e30f;
#pragma unroll
    for (int p = 0; p < cP; p++) {
        float a = 0.f;
#pragma unroll
        for (int j = 0; j < cBANDS; j++) {
            float d = rs[j] - prototypes[p * cBANDS + j];
            a += d * d;
        }
        logits[p] = -(a * (1.0f / cBANDS)) * 4.0f;   // * sqrt(16)
        mx = fmaxf(mx, logits[p]);
    }
    float assign[cP];
    float denom = 0.f;
#pragma unroll
    for (int p = 0; p < cP; p++) { assign[p] = expf(logits[p] - mx); denom += assign[p]; }
    float invden = 1.0f / denom;
#pragma unroll
    for (int p = 0; p < cP; p++) assign[p] *= invden;
    for (int d = 0; d < cD; d++) {
        float r[cE];
        float rmx = -1e30f;
#pragma unroll
        for (int e = 0; e < cE; e++) {
            float a = 0.f;
#pragma unroll
            for (int p = 0; p < cP; p++) a += assign[p] * route_lib[(p * cD + d) * cE + e];
            r[e] = a;
            rmx = fmaxf(rmx, a);
        }
        float rden = 0.f;
#pragma unroll
        for (int e = 0; e < cE; e++) { r[e] = expf(r[e] - rmx); rden += r[e]; }
        float rinv = 1.0f / rden;
#pragma unroll
        for (int e = 0; e < cE; e++) routes[(b * cD + d) * cE + e] = r[e] * rinv;
        for (int c = 0; c < cH; c++) {
            float a = 0.f;
#pragma unroll
            for (int p = 0; p < cP; p++) a += assign[p] * gain_lib[(p * cD + d) * cH + c];
            gains[((size_t)b * cD + d) * cH + c] = 1.0f + 0.5f * tanhf(a);
        }
    }
}

// ---------------- stem conv (K=3, pad 1) + BN + GELU ----------------
constexpr int STT = 256;
__global__ __launch_bounds__(256) void k_stem(const float* __restrict__ x,
                                              const float* __restrict__ stem_w,
                                              const float* __restrict__ bn_g,
                                              const float* __restrict__ bn_b,
                                              float* __restrict__ z) {
    __shared__ float xs[cCIN][STT + 2];
    __shared__ float ws[cH * cCIN * 3];
    int blk = blockIdx.x;
    int b = blk / (cT / STT);
    int t0 = (blk % (cT / STT)) * STT;
    for (int i = threadIdx.x; i < cH * cCIN * 3; i += 256) ws[i] = stem_w[i];
    for (int i = threadIdx.x; i < cCIN * (STT + 2); i += 256) {
        int c = i / (STT + 2), tt = i % (STT + 2);
        int gt = t0 + tt - 1;
        xs[c][tt] = (gt >= 0 && gt < cT) ? x[((size_t)b * cCIN + c) * cT + gt] : 0.f;
    }
    __syncthreads();
    int tt = threadIdx.x;
    float xv[cCIN][3];
#pragma unroll
    for (int c = 0; c < cCIN; c++)
#pragma unroll
        for (int k = 0; k < 3; k++) xv[c][k] = xs[c][tt + k];
    int gt = t0 + tt;
    float bnrs = rsqrtf(1.0f + cEPS);
    for (int h = 0; h < cH; h++) {
        const float* w = &ws[h * cCIN * 3];
        float acc = 0.f;
#pragma unroll
        for (int c = 0; c < cCIN; c++)
#pragma unroll
            for (int k = 0; k < 3; k++) acc += xv[c][k] * w[c * 3 + k];
        float v = acc * (bn_g[h] * bnrs) + bn_b[h];
        z[((size_t)b * cH + h) * cT + gt] = gelu_exact(v);
    }
}

// ---------------- GroupNorm(1,C) stats: partial sums via atomics ----------------
constexpr int GN_CHUNKS = 64;
__global__ __launch_bounds__(256) void k_gn_stats(const float* __restrict__ z,
                                                  float* __restrict__ sums) {
    int blk = blockIdx.x;
    int b = blk / GN_CHUNKS, chunk = blk % GN_CHUNKS;
    const int CN = cH * cT / GN_CHUNKS;   // 12288
    const float* zp = z + (size_t)b * cH * cT + (size_t)chunk * CN;
    float s = 0.f, sq = 0.f;
    for (int i = threadIdx.x; i < CN; i += 256) {
        float v = zp[i];
        s += v; sq += v * v;
    }
    __shared__ float r1[256], r2[256];
    r1[threadIdx.x] = s; r2[threadIdx.x] = sq;
    __syncthreads();
    for (int st = 128; st > 0; st >>= 1) {
        if (threadIdx.x < st) {
            r1[threadIdx.x] += r1[threadIdx.x + st];
            r2[threadIdx.x] += r2[threadIdx.x + st];
        }
        __syncthreads();
    }
    if (threadIdx.x == 0) {
        atomicAdd(&sums[b * 2], r1[0]);
        atomicAdd(&sums[b * 2 + 1], r2[0]);
    }
}

// ---------------- block part 1: GN + dilated dwconv experts + mix + BN + GELU + residual ----------------
__global__ __launch_bounds__(256) void k_block1(
    const float* __restrict__ zin, float* __restrict__ zout,
    const float* __restrict__ sums, const float* __restrict__ g1,
    const float* __restrict__ b1, const float* __restrict__ ew,
    const float* __restrict__ mw, const float* __restrict__ mg,
    const float* __restrict__ mb, const float* __restrict__ routes,
    const float* __restrict__ gains, int d) {
    __shared__ float zn[cH][TT + 2 * HALO];   // 192 x 112
    __shared__ float mx[cH][TT];              // 192 x 64
    __shared__ float rte[cE];
    __shared__ float gn[cH];
    int blk = blockIdx.x;
    int b = blk / (cT / TT);
    int t0 = (blk % (cT / TT)) * TT;
    const float invN = 1.0f / (float)(cH * cT);
    float mean = sums[b * 2] * invN;
    float var = sums[b * 2 + 1] * invN - mean * mean;
    float rstd = rsqrtf(var + cEPS);
    if (threadIdx.x < cE) rte[threadIdx.x] = routes[(b * cD + d) * cE + threadIdx.x];
    for (int c = threadIdx.x; c < cH; c += 256) gn[c] = gains[((size_t)b * cD + d) * cH + c];
    // stage normalized tile with halo (zeros beyond [0,T) = conv zero-pad)
    for (int i = threadIdx.x; i < cH * (TT + 2 * HALO); i += 256) {
        int c = i / (TT + 2 * HALO), tt = i % (TT + 2 * HALO);
        int gt = t0 + tt - HALO;
        float v = 0.f;
        if (gt >= 0 && gt < cT)
            v = (zin[((size_t)b * cH + c) * cT + gt] - mean) * rstd * g1[c] + b1[c];
        zn[c][tt] = v;
    }
    __syncthreads();
    // depthwise dilated convs, routed mix, gains
    for (int i = threadIdx.x; i < cH * TT; i += 256) {
        int c = i / TT, tt = i % TT;
        float acc = 0.f;
#pragma unroll
        for (int e = 0; e < cE; e++) {
            int dil = 1 << e;
            const float* w = &ew[(e * cH + c) * cK];
            float a = 0.f;
#pragma unroll
            for (int k = 0; k < cK; k++) a += zn[c][tt + HALO + (k - 3) * dil] * w[k];
            acc += rte[e] * a;
        }
        mx[c][tt] = acc * gn[c];
    }
    __syncthreads();
    // channel mix matmul + BN + GELU + residual (4 t's per thread)
    float bnrs = rsqrtf(1.0f + cEPS);
    for (int idx = threadIdx.x; idx < cH * (TT / 4); idx += 256) {
        int o = idx / (TT / 4);
        int tt = (idx % (TT / 4)) * 4;
        const float* w = &mw[o * cH];
        float a0 = 0.f, a1 = 0.f, a2 = 0.f, a3 = 0.f;
        for (int c = 0; c < cH; c++) {
            float wv = w[c];
            float4 m4 = *reinterpret_cast<const float4*>(&mx[c][tt]);
            a0 += wv * m4.x; a1 += wv * m4.y; a2 += wv * m4.z; a3 += wv * m4.w;
        }
        float sc = mg[o] * bnrs, be = mb[o];
        size_t base = ((size_t)b * cH + o) * cT + t0 + tt;
        zout[base + 0] = zin[base + 0] + gelu_exact(a0 * sc + be);
        zout[base + 1] = zin[base + 1] + gelu_exact(a1 * sc + be);
        zout[base + 2] = zin[base + 2] + gelu_exact(a2 * sc + be);
        zout[base + 3] = zin[base + 3] + gelu_exact(a3 * sc + be);
    }
}

// ---------------- block part 2: GN + MLP (w1,gelu,w2) + residual, in-place ----------------
__global__ __launch_bounds__(256) void k_block2(
    float* __restrict__ z, const float* __restrict__ sums,
    const float* __restrict__ g2, const float* __restrict__ b2,
    const float* __restrict__ w1, const float* __restrict__ bb1,
    const float* __restrict__ w2, const float* __restrict__ bb2) {
    __shared__ float zn[cH][TT];    // 48 KB
    __shared__ float hs[cHM][TT];   // 96 KB
    int blk = blockIdx.x;
    int b = blk / (cT / TT);
    int t0 = (blk % (cT / TT)) * TT;
    const float invN = 1.0f / (float)(cH * cT);
    float mean = sums[b * 2] * invN;
    float var = sums[b * 2 + 1] * invN - mean * mean;
    float rstd = rsqrtf(var + cEPS);
    for (int i = threadIdx.x; i < cH * TT; i += 256) {
        int c = i / TT, tt = i % TT;
        zn[c][tt] = (z[((size_t)b * cH + c) * cT + t0 + tt] - mean) * rstd * g2[c] + b2[c];
    }
    __syncthreads();
    for (int idx = threadIdx.x; idx < cHM * (TT / 4); idx += 256) {
        int m = idx / (TT / 4);
        int tt = (idx % (TT / 4)) * 4;
        const float* w = &w1[m * cH];
        float a0 = bb1[m], a1 = a0, a2 = a0, a3 = a0;
        for (int c = 0; c < cH; c++) {
            float wv = w[c];
            float4 v4 = *reinterpret_cast<const float4*>(&zn[c][tt]);
            a0 += wv * v4.x; a1 += wv * v4.y; a2 += wv * v4.z; a3 += wv * v4.w;
        }
        hs[m][tt + 0] = gelu_exact(a0);
        hs[m][tt + 1] = gelu_exact(a1);
        hs[m][tt + 2] = gelu_exact(a2);
        hs[m][tt + 3] = gelu_exact(a3);
    }
    __syncthreads();
    for (int idx = threadIdx.x; idx < cH * (TT / 4); idx += 256) {
        int o = idx / (TT / 4);
        int tt = (idx % (TT / 4)) * 4;
        const float* w = &w2[o * cHM];
        float a0 = bb2[o], a1 = a0, a2 = a0, a3 = a0;
        for (int m = 0; m < cHM; m++) {
            float wv = w[m];
            float4 v4 = *reinterpret_cast<const float4*>(&hs[m][tt]);
            a0 += wv * v4.x; a1 += wv * v4.y; a2 += wv * v4.z; a3 += wv * v4.w;
        }
        size_t base = ((size_t)b * cH + o) * cT + t0 + tt;
        z[base + 0] += a0; z[base + 1] += a1; z[base + 2] += a2; z[base + 3] += a3;
    }
}

// ---------------- global average pool ----------------
__global__ __launch_bounds__(256) void k_pool(const float* __restrict__ z,
                                              float* __restrict__ pooled) {
    int bh = blockIdx.x;
    const float* zp = z + (size_t)bh * cT;
    float s = 0.f;
    for (int t = threadIdx.x; t < cT; t += 256) s += zp[t];
    __shared__ float red[256];
    red[threadIdx.x] = s;
    __syncthreads();
    for (int st = 128; st > 0; st >>= 1) {
        if (threadIdx.x < st) red[threadIdx.x] += red[threadIdx.x + st];
        __syncthreads();
    }
    if (threadIdx.x == 0) pooled[bh] = red[0] * (1.0f / cT);
}

// ---------------- head ----------------
__global__ __launch_bounds__(256) void k_head(const float* __restrict__ pooled,
                                              const float* __restrict__ hw,
                                              const float* __restrict__ hb,
                                              float* __restrict__ out) {
    int i = blockIdx.x * 256 + threadIdx.x;
    if (i >= cB * cNCLS) return;
    int b = i / cNCLS, n = i % cNCLS;
    float acc = hb[n];
    const float* pw = pooled + b * cH;
    const float* wr = hw + n * cH;
    for (int h = 0; h < cH; h++) acc += pw[h] * wr[h];
    out[i] = acc;
}

extern "C" void kernel_launch(void* const* d_in, const int* in_sizes, int n_in,
                              void* d_out, int out_size, void* d_ws, size_t ws_size,
                              hipStream_t stream) {
    const float* x          = (const float*)d_in[0];
    const float* stem_w     = (const float*)d_in[1];
    const float* stem_bn_g  = (const float*)d_in[2];
    const float* stem_bn_b  = (const float*)d_in[3];
    const float* ln_g       = (const float*)d_in[4];
    const float* ln_b       = (const float*)d_in[5];
    const float* proj_w     = (const float*)d_in[6];
    const float* prototypes = (const float*)d_in[7];
    const float* route_lib  = (const float*)d_in[8];
    const float* gain_lib   = (const float*)d_in[9];
    const float* norm1_g    = (const float*)d_in[10];
    const float* norm1_b    = (const float*)d_in[11];
    const float* expert_w   = (const float*)d_in[12];
    const float* mix_w      = (const float*)d_in[13];
    const float* mix_bn_g   = (const float*)d_in[14];
    const float* mix_bn_b   = (const float*)d_in[15];
    const float* norm2_g    = (const float*)d_in[16];
    const float* norm2_b    = (const float*)d_in[17];
    const float* mlp_w1     = (const float*)d_in[18];
    const float* mlp_b1     = (const float*)d_in[19];
    const float* mlp_w2     = (const float*)d_in[20];
    const float* mlp_b2     = (const float*)d_in[21];
    const float* head_w     = (const float*)d_in[22];
    const float* head_b     = (const float*)d_in[23];

    float* ws = (float*)d_ws;
    size_t off = 0;
    const size_t ZN = (size_t)cB * cH * cT;
    float* zA      = ws + off; off += ZN;
    float* zB      = ws + off; off += ZN;
    float* mag     = ws + off; off += (size_t)cB * cBINS;
    float* sums    = ws + off; off += 2 * cD * cB * 2;    // 8 regions of [B][2]
    float* basis   = ws + off; off += (size_t)cBANDS * cBINS;
    float* summary = ws + off; off += cB * cBANDS;
    float* routes  = ws + off; off += cB * cD * cE;
    float* gains   = ws + off; off += (size_t)cB * cD * cH;
    float* pooled  = ws + off; off += cB * cH;

    // zero atomic accumulators (mag + sums are contiguous)
    int nz = cB * cBINS + 2 * cD * cB * 2;
    k_zero<<<(nz + 255) / 256, 256, 0, stream>>>(mag, nz);

    // spectral summary + router
    k_fft_mag<<<cB * cCIN, 256, 0, stream>>>(x, mag);
    k_basis<<<cBANDS, 256, 0, stream>>>(basis);
    k_summary<<<cB, 256, 0, stream>>>(mag, basis, summary);
    k_router<<<1, 64, 0, stream>>>(summary, ln_g, ln_b, proj_w, prototypes,
                                   route_lib, gain_lib, routes, gains);

    // stem
    k_stem<<<cB * (cT / STT), 256, 0, stream>>>(x, stem_w, stem_bn_g, stem_bn_b, zA);

    // routed temporal blocks (ping-pong zA/zB: block1 reads halo from zin, writes zout)
    float* zi = zA;
    float* zo = zB;
    for (int d = 0; d < cD; d++) {
        float* s1 = sums + (size_t)(2 * d + 0) * cB * 2;
        float* s2 = sums + (size_t)(2 * d + 1) * cB * 2;
        k_gn_stats<<<cB * GN_CHUNKS, 256, 0, stream>>>(zi, s1);
        k_block1<<<cB * (cT / TT), 256, 0, stream>>>(
            zi, zo, s1, norm1_g + d * cH, norm1_b + d * cH,
            expert_w + (size_t)d * cE * cH * cK, mix_w + (size_t)d * cH * cH,
            mix_bn_g + d * cH, mix_bn_b + d * cH, routes, gains, d);
        k_gn_stats<<<cB * GN_CHUNKS, 256, 0, stream>>>(zo, s2);
        k_block2<<<cB * (cT / TT), 256, 0, stream>>>(
            zo, s2, norm2_g + d * cH, norm2_b + d * cH,
            mlp_w1 + (size_t)d * cHM * cH, mlp_b1 + d * cHM,
            mlp_w2 + (size_t)d * cH * cHM, mlp_b2 + d * cH);
        float* t = zi; zi = zo; zo = t;
    }

    // head
    k_pool<<<cB * cH, 256, 0, stream>>>(zi, pooled);
    k_head<<<(cB * cNCLS + 255) / 256, 256, 0, stream>>>(pooled, head_w, head_b,
                                                         (float*)d_out);
}

// Round 2
// 2445.170 us; speedup vs baseline: 3.0308x; 3.0308x over previous
//
#include <hip/hip_runtime.h>
#include <math.h>

constexpr int cB = 32, cCIN = 16, cT = 4096, cH = 192, cD = 4, cE = 4, cK = 7;
constexpr int cBANDS = 16, cP = 8, cHM = 384, cNCLS = 50, cBINS = 2049;
constexpr float cEPS = 1e-5f;
constexpr int TT = 64, HALO = 24;          // block time tile, dwconv halo (3*8)
constexpr float INV_SQRT2 = 0.7071067811865475f;

typedef __bf16 bf16_t;
typedef bf16_t bf16x8 __attribute__((ext_vector_type(8)));
typedef float f32x4 __attribute__((ext_vector_type(4)));

__device__ __forceinline__ float gelu_exact(float v) {
    return 0.5f * v * (1.0f + erff(v * INV_SQRT2));
}
__device__ __forceinline__ unsigned short f2bf(float f) {
    union { float f; unsigned u; } v; v.f = f;
    unsigned r = (v.u + 0x7FFFu + ((v.u >> 16) & 1u)) >> 16;
    return (unsigned short)r;
}
__device__ __forceinline__ float bf2f(unsigned short u) {
    union { unsigned u; float f; } v; v.u = ((unsigned)u) << 16;
    return v.f;
}

// ---------------- zero scratch ----------------
__global__ __launch_bounds__(256) void k_zero(float* __restrict__ p, int n) {
    int i = blockIdx.x * 256 + threadIdx.x;
    if (i < n) p[i] = 0.f;
}

// ---------------- fp32 -> bf16 weight conversion ----------------
__global__ __launch_bounds__(256) void k_cvt(const float* __restrict__ src,
                                             unsigned short* __restrict__ dst, int n) {
    int i = blockIdx.x * 256 + threadIdx.x;
    if (i < n) dst[i] = f2bf(src[i]);
}

// ---------------- twiddle table ----------------
__global__ __launch_bounds__(256) void k_twiddle(float2* __restrict__ tw) {
    int ls = blockIdx.x;
    int n = cT >> ls;
    int cnt = n >> 1;
    int base = cT - (cT >> ls);
    for (int p = threadIdx.x; p < cnt; p += 256) {
        float ang = -6.283185307179586f * (float)p / (float)n;
        float sv, cv;
        sincosf(ang, &sv, &cv);
        tw[base + p] = make_float2(cv, sv);
    }
}

// ---------------- FFT magnitude: one block per (b, cin) ----------------
__global__ __launch_bounds__(256) void k_fft_mag(const float* __restrict__ x,
                                                 const float2* __restrict__ tw,
                                                 float* __restrict__ mag) {
    __shared__ float Sr[2][cT];
    __shared__ float Si[2][cT];
    int b = blockIdx.x / cCIN, c = blockIdx.x % cCIN;
    const float* xp = x + ((size_t)b * cCIN + c) * cT;
    for (int t = threadIdx.x; t < cT; t += 256) { Sr[0][t] = xp[t]; Si[0][t] = 0.f; }
    __syncthreads();
    int cur = 0, n = cT, ls = 0;
    while (n > 1) {
        int s = 1 << ls;
        int twb = cT - (cT >> ls);
        for (int j = threadIdx.x; j < cT / 2; j += 256) {
            int p = j >> ls;
            float2 w = tw[twb + p];
            float wr = w.x, wi = w.y;
            int ia = j, ib = j + cT / 2;
            float ar = Sr[cur][ia], ai = Si[cur][ia];
            float br = Sr[cur][ib], bi = Si[cur][ib];
            int oa = j + (j & ~(s - 1));
            int ob = oa + s;
            Sr[cur ^ 1][oa] = ar + br;
            Si[cur ^ 1][oa] = ai + bi;
            float tr = ar - br, ti = ai - bi;
            Sr[cur ^ 1][ob] = tr * wr - ti * wi;
            Si[cur ^ 1][ob] = tr * wi + ti * wr;
        }
        __syncthreads();
        cur ^= 1; n >>= 1; ls += 1;
    }
    const float scale = (1.0f / 64.0f) * (1.0f / 16.0f); // ortho norm, mean over CIN
    for (int k = threadIdx.x; k < cBINS; k += 256) {
        float re = Sr[cur][k], im = Si[cur][k];
        atomicAdd(&mag[b * cBINS + k], sqrtf(re * re + im * im) * scale);
    }
}

// ---------------- RBF basis (normalized rows) ----------------
__global__ __launch_bounds__(256) void k_basis(float* __restrict__ basis) {
    __shared__ float vals[cBINS];
    __shared__ float red[256];
    int band = blockIdx.x;
    float cb = (float)band / 15.0f;
    float inv_w = 15.0f / 1.5f;
    float local = 0.f;
    for (int k = threadIdx.x; k < cBINS; k += 256) {
        float f = (float)k / 2048.0f;
        float u = (f - cb) * inv_w;
        float v = expf(-0.5f * u * u);
        vals[k] = v;
        local += v;
    }
    red[threadIdx.x] = local;
    __syncthreads();
    for (int s = 128; s > 0; s >>= 1) {
        if (threadIdx.x < s) red[threadIdx.x] += red[threadIdx.x + s];
        __syncthreads();
    }
    float inv_sum = 1.0f / fmaxf(red[0], 1e-8f);
    for (int k = threadIdx.x; k < cBINS; k += 256)
        basis[band * cBINS + k] = vals[k] * inv_sum;
}

// ---------------- summary = log1p(mag) @ basis.T ----------------
__global__ __launch_bounds__(256) void k_summary(const float* __restrict__ mag,
                                                 const float* __restrict__ basis,
                                                 float* __restrict__ summary) {
    int b = blockIdx.x;
    float acc[cBANDS];
#pragma unroll
    for (int i = 0; i < cBANDS; i++) acc[i] = 0.f;
    for (int k = threadIdx.x; k < cBINS; k += 256) {
        float lm = log1pf(mag[b * cBINS + k]);
#pragma unroll
        for (int band = 0; band < cBANDS; band++) acc[band] += lm * basis[band * cBINS + k];
    }
    __shared__ float red[cBANDS][256];
#pragma unroll
    for (int band = 0; band < cBANDS; band++) red[band][threadIdx.x] = acc[band];
    __syncthreads();
    for (int s = 128; s > 0; s >>= 1) {
        if (threadIdx.x < s)
#pragma unroll
            for (int band = 0; band < cBANDS; band++)
                red[band][threadIdx.x] += red[band][threadIdx.x + s];
        __syncthreads();
    }
    if (threadIdx.x < cBANDS) summary[b * cBANDS + threadIdx.x] = red[threadIdx.x][0];
}

// ---------------- router ----------------
__global__ __launch_bounds__(64) void k_router(
    const float* __restrict__ summary, const float* __restrict__ ln_g,
    const float* __restrict__ ln_b, const float* __restrict__ proj_w,
    const float* __restrict__ prototypes, const float* __restrict__ route_lib,
    const float* __restrict__ gain_lib, float* __restrict__ routes,
    float* __restrict__ gains) {
    int b = threadIdx.x;
    if (b >= cB) return;
    float s[cBANDS];
    float mean = 0.f;
#pragma unroll
    for (int i = 0; i < cBANDS; i++) { s[i] = summary[b * cBANDS + i]; mean += s[i]; }
    mean *= (1.0f / cBANDS);
    float var = 0.f;
#pragma unroll
    for (int i = 0; i < cBANDS; i++) { float d = s[i] - mean; var += d * d; }
    var *= (1.0f / cBANDS);
    float rstd = rsqrtf(var + cEPS);
#pragma unroll
    for (int i = 0; i < cBANDS; i++) s[i] = (s[i] - mean) * rstd * ln_g[i] + ln_b[i];
    float rs[cBANDS];
#pragma unroll
    for (int j = 0; j < cBANDS; j++) {
        float a = 0.f;
#pragma unroll
        for (int i = 0; i < cBANDS; i++) a += s[i] * proj_w[j * cBANDS + i];
        rs[j] = a;
    }
    float logits[cP];
    float mx = -1e30f;
#pragma unroll
    for (int p = 0; p < cP; p++) {
        float a = 0.f;
#pragma unroll
        for (int j = 0; j < cBANDS; j++) {
            float d = rs[j] - prototypes[p * cBANDS + j];
            a += d * d;
        }
        logits[p] = -(a * (1.0f / cBANDS)) * 4.0f;
        mx = fmaxf(mx, logits[p]);
    }
    float assign[cP];
    float denom = 0.f;
#pragma unroll
    for (int p = 0; p < cP; p++) { assign[p] = expf(logits[p] - mx); denom += assign[p]; }
    float invden = 1.0f / denom;
#pragma unroll
    for (int p = 0; p < cP; p++) assign[p] *= invden;
    for (int d = 0; d < cD; d++) {
        float r[cE];
        float rmx = -1e30f;
#pragma unroll
        for (int e = 0; e < cE; e++) {
            float a = 0.f;
#pragma unroll
            for (int p = 0; p < cP; p++) a += assign[p] * route_lib[(p * cD + d) * cE + e];
            r[e] = a;
            rmx = fmaxf(rmx, a);
        }
        float rden = 0.f;
#pragma unroll
        for (int e = 0; e < cE; e++) { r[e] = expf(r[e] - rmx); rden += r[e]; }
        float rinv = 1.0f / rden;
#pragma unroll
        for (int e = 0; e < cE; e++) routes[(b * cD + d) * cE + e] = r[e] * rinv;
        for (int c = 0; c < cH; c++) {
            float a = 0.f;
#pragma unroll
            for (int p = 0; p < cP; p++) a += assign[p] * gain_lib[(p * cD + d) * cH + c];
            gains[((size_t)b * cD + d) * cH + c] = 1.0f + 0.5f * tanhf(a);
        }
    }
}

// ---------------- stem conv (K=3, pad 1) + BN + GELU + fused stats ----------------
constexpr int STT = 256;
__global__ __launch_bounds__(256) void k_stem(const float* __restrict__ x,
                                              const float* __restrict__ stem_w,
                                              const float* __restrict__ bn_g,
                                              const float* __restrict__ bn_b,
                                              float* __restrict__ z,
                                              float* __restrict__ sums_out) {
    __shared__ float xs[cCIN][STT + 2];
    __shared__ float ws[cH * cCIN * 3];
    int blk = blockIdx.x;
    int b = blk / (cT / STT);
    int t0 = (blk % (cT / STT)) * STT;
    for (int i = threadIdx.x; i < cH * cCIN * 3; i += 256) ws[i] = stem_w[i];
    for (int i = threadIdx.x; i < cCIN * (STT + 2); i += 256) {
        int c = i / (STT + 2), tt = i % (STT + 2);
        int gt = t0 + tt - 1;
        xs[c][tt] = (gt >= 0 && gt < cT) ? x[((size_t)b * cCIN + c) * cT + gt] : 0.f;
    }
    __syncthreads();
    int tt = threadIdx.x;
    float xv[cCIN][3];
#pragma unroll
    for (int c = 0; c < cCIN; c++)
#pragma unroll
        for (int k = 0; k < 3; k++) xv[c][k] = xs[c][tt + k];
    int gt = t0 + tt;
    float bnrs = rsqrtf(1.0f + cEPS);
    float s = 0.f, q = 0.f;
    for (int h = 0; h < cH; h++) {
        const float* w = &ws[h * cCIN * 3];
        float acc = 0.f;
#pragma unroll
        for (int c = 0; c < cCIN; c++)
#pragma unroll
            for (int k = 0; k < 3; k++) acc += xv[c][k] * w[c * 3 + k];
        float v = acc * (bn_g[h] * bnrs) + bn_b[h];
        float res = gelu_exact(v);
        z[((size_t)b * cH + h) * cT + gt] = res;
        s += res; q += res * res;
    }
#pragma unroll
    for (int off = 32; off > 0; off >>= 1) { s += __shfl_down(s, off); q += __shfl_down(q, off); }
    if ((threadIdx.x & 63) == 0) {
        atomicAdd(&sums_out[b * 2], s);
        atomicAdd(&sums_out[b * 2 + 1], q);
    }
}

// ---------------- block part 1: GN + dwconv experts + routed mix (MFMA) + BN + GELU + residual ----------------
__global__ __launch_bounds__(256, 2) void k_block1(
    const float* __restrict__ zin, float* __restrict__ zout,
    const float* __restrict__ sums_in, float* __restrict__ sums_out,
    const float* __restrict__ g1, const float* __restrict__ b1,
    const float* __restrict__ ew, const unsigned short* __restrict__ mwb,
    const float* __restrict__ mg, const float* __restrict__ mb,
    const float* __restrict__ routes, const float* __restrict__ gains, int d) {
    __shared__ unsigned short zn[cH][112];     // normalized tile + halo, bf16
    __shared__ unsigned short mxT[TT][200];    // mixed^T, bf16, padded rows (400B)
    __shared__ float rte[cE];
    __shared__ float gn[cH];
    int blk = blockIdx.x;
    int b = blk / (cT / TT);
    int t0 = (blk % (cT / TT)) * TT;
    const float invN = 1.0f / (float)(cH * cT);
    float mean = sums_in[b * 2] * invN;
    float var = sums_in[b * 2 + 1] * invN - mean * mean;
    float rstd = rsqrtf(var + cEPS);
    if (threadIdx.x < cE) rte[threadIdx.x] = routes[(b * cD + d) * cE + threadIdx.x];
    if (threadIdx.x < cH) gn[threadIdx.x] = gains[((size_t)b * cD + d) * cH + threadIdx.x];
    for (int i = threadIdx.x; i < cH * (TT + 2 * HALO); i += 256) {
        int c = i / 112, tt = i % 112;
        int gt = t0 + tt - HALO;
        float v = 0.f;
        if (gt >= 0 && gt < cT)
            v = (zin[((size_t)b * cH + c) * cT + gt] - mean) * rstd * g1[c] + b1[c];
        zn[c][tt] = f2bf(v);
    }
    __syncthreads();
    // depthwise dilated convs + routed mix + gain -> mxT (bf16)
    for (int i = threadIdx.x; i < cH * TT; i += 256) {
        int c = i >> 6, tt = i & 63;
        float acc = 0.f;
#pragma unroll
        for (int e = 0; e < cE; e++) {
            int dil = 1 << e;
            const float* w = &ew[(e * cH + c) * cK];
            float a = 0.f;
#pragma unroll
            for (int k = 0; k < cK; k++) a += bf2f(zn[c][tt + HALO + (k - 3) * dil]) * w[k];
            acc += rte[e] * a;
        }
        mxT[tt][c] = f2bf(acc * gn[c]);
    }
    __syncthreads();
    // mix matmul: out[o][t] = sum_c mw[o][c]*mx[c][t]; M=192, K=192, N=64
    int lane = threadIdx.x & 63, wid = threadIdx.x >> 6;
    int lrow = lane & 15;
    int lk8 = (lane >> 4) << 3;
    int r0 = (lane >> 4) << 2;
    int mbase = wid * 48;
    f32x4 acc[3][4];
#pragma unroll
    for (int mt = 0; mt < 3; mt++)
#pragma unroll
        for (int nt = 0; nt < 4; nt++)
#pragma unroll
            for (int r = 0; r < 4; r++) acc[mt][nt][r] = 0.f;
    for (int kk = 0; kk < 6; kk++) {
        int k0 = kk * 32 + lk8;
        bf16x8 a0 = *reinterpret_cast<const bf16x8*>(&mwb[(size_t)(mbase + lrow) * cH + k0]);
        bf16x8 a1 = *reinterpret_cast<const bf16x8*>(&mwb[(size_t)(mbase + 16 + lrow) * cH + k0]);
        bf16x8 a2 = *reinterpret_cast<const bf16x8*>(&mwb[(size_t)(mbase + 32 + lrow) * cH + k0]);
#pragma unroll
        for (int nt = 0; nt < 4; nt++) {
            bf16x8 bf = *reinterpret_cast<const bf16x8*>(&mxT[nt * 16 + lrow][k0]);
            acc[0][nt] = __builtin_amdgcn_mfma_f32_16x16x32_bf16(a0, bf, acc[0][nt], 0, 0, 0);
            acc[1][nt] = __builtin_amdgcn_mfma_f32_16x16x32_bf16(a1, bf, acc[1][nt], 0, 0, 0);
            acc[2][nt] = __builtin_amdgcn_mfma_f32_16x16x32_bf16(a2, bf, acc[2][nt], 0, 0, 0);
        }
    }
    float bnrs = rsqrtf(1.0f + cEPS);
    float s = 0.f, q = 0.f;
#pragma unroll
    for (int mt = 0; mt < 3; mt++) {
#pragma unroll
        for (int nt = 0; nt < 4; nt++) {
#pragma unroll
            for (int r = 0; r < 4; r++) {
                int o = mbase + mt * 16 + r0 + r;
                int t = t0 + nt * 16 + lrow;
                size_t idx = ((size_t)b * cH + o) * cT + t;
                float val = zin[idx] + gelu_exact(acc[mt][nt][r] * (mg[o] * bnrs) + mb[o]);
                zout[idx] = val;
                s += val; q += val * val;
            }
        }
    }
#pragma unroll
    for (int off = 32; off > 0; off >>= 1) { s += __shfl_down(s, off); q += __shfl_down(q, off); }
    if (lane == 0) {
        atomicAdd(&sums_out[b * 2], s);
        atomicAdd(&sums_out[b * 2 + 1], q);
    }
}

// ---------------- block part 2: GN + MLP (w1 GELU w2, MFMA) + residual, in-place ----------------
__global__ __launch_bounds__(256, 2) void k_block2(
    float* __restrict__ z, const float* __restrict__ sums_in,
    float* __restrict__ sums_out,
    const float* __restrict__ g2, const float* __restrict__ b2,
    const unsigned short* __restrict__ w1b, const float* __restrict__ bb1,
    const unsigned short* __restrict__ w2b, const float* __restrict__ bb2) {
    __shared__ unsigned short znT[TT][200];   // [t][c], 400B rows
    __shared__ unsigned short hT[TT][392];    // [t][m], 784B rows
    int blk = blockIdx.x;
    int b = blk / (cT / TT);
    int t0 = (blk % (cT / TT)) * TT;
    const float invN = 1.0f / (float)(cH * cT);
    float mean = sums_in[b * 2] * invN;
    float var = sums_in[b * 2 + 1] * invN - mean * mean;
    float rstd = rsqrtf(var + cEPS);
    for (int i = threadIdx.x; i < cH * (TT / 4); i += 256) {
        int c = i >> 4, t4 = (i & 15) << 2;
        float4 v = *reinterpret_cast<const float4*>(&z[((size_t)b * cH + c) * cT + t0 + t4]);
        float gc = g2[c], bc = b2[c];
        znT[t4 + 0][c] = f2bf((v.x - mean) * rstd * gc + bc);
        znT[t4 + 1][c] = f2bf((v.y - mean) * rstd * gc + bc);
        znT[t4 + 2][c] = f2bf((v.z - mean) * rstd * gc + bc);
        znT[t4 + 3][c] = f2bf((v.w - mean) * rstd * gc + bc);
    }
    __syncthreads();
    int lane = threadIdx.x & 63, wid = threadIdx.x >> 6;
    int lrow = lane & 15;
    int lk8 = (lane >> 4) << 3;
    int r0 = (lane >> 4) << 2;
    // ---- w1: M=384, K=192 ----
    for (int chunk = 0; chunk < 2; chunk++) {
        int mbase = wid * 96 + chunk * 48;
        f32x4 acc[3][4];
#pragma unroll
        for (int mt = 0; mt < 3; mt++) {
#pragma unroll
            for (int r = 0; r < 4; r++) {
                float bv = bb1[mbase + mt * 16 + r0 + r];
                acc[mt][0][r] = bv; acc[mt][1][r] = bv; acc[mt][2][r] = bv; acc[mt][3][r] = bv;
            }
        }
        for (int kk = 0; kk < 6; kk++) {
            int k0 = kk * 32 + lk8;
            bf16x8 a0 = *reinterpret_cast<const bf16x8*>(&w1b[(size_t)(mbase + lrow) * cH + k0]);
            bf16x8 a1 = *reinterpret_cast<const bf16x8*>(&w1b[(size_t)(mbase + 16 + lrow) * cH + k0]);
            bf16x8 a2 = *reinterpret_cast<const bf16x8*>(&w1b[(size_t)(mbase + 32 + lrow) * cH + k0]);
#pragma unroll
            for (int nt = 0; nt < 4; nt++) {
                bf16x8 bf = *reinterpret_cast<const bf16x8*>(&znT[nt * 16 + lrow][k0]);
                acc[0][nt] = __builtin_amdgcn_mfma_f32_16x16x32_bf16(a0, bf, acc[0][nt], 0, 0, 0);
                acc[1][nt] = __builtin_amdgcn_mfma_f32_16x16x32_bf16(a1, bf, acc[1][nt], 0, 0, 0);
                acc[2][nt] = __builtin_amdgcn_mfma_f32_16x16x32_bf16(a2, bf, acc[2][nt], 0, 0, 0);
            }
        }
#pragma unroll
        for (int mt = 0; mt < 3; mt++) {
            int o0 = mbase + mt * 16 + r0;
#pragma unroll
            for (int nt = 0; nt < 4; nt++) {
                int t = nt * 16 + lrow;
                ushort4 pk;
                pk.x = f2bf(gelu_exact(acc[mt][nt][0]));
                pk.y = f2bf(gelu_exact(acc[mt][nt][1]));
                pk.z = f2bf(gelu_exact(acc[mt][nt][2]));
                pk.w = f2bf(gelu_exact(acc[mt][nt][3]));
                *reinterpret_cast<ushort4*>(&hT[t][o0]) = pk;
            }
        }
    }
    __syncthreads();
    // ---- w2: M=192, K=384 ----
    {
        int mbase = wid * 48;
        f32x4 acc[3][4];
#pragma unroll
        for (int mt = 0; mt < 3; mt++) {
#pragma unroll
            for (int r = 0; r < 4; r++) {
                float bv = bb2[mbase + mt * 16 + r0 + r];
                acc[mt][0][r] = bv; acc[mt][1][r] = bv; acc[mt][2][r] = bv; acc[mt][3][r] = bv;
            }
        }
        for (int kk = 0; kk < 12; kk++) {
            int k0 = kk * 32 + lk8;
            bf16x8 a0 = *reinterpret_cast<const bf16x8*>(&w2b[(size_t)(mbase + lrow) * cHM + k0]);
            bf16x8 a1 = *reinterpret_cast<const bf16x8*>(&w2b[(size_t)(mbase + 16 + lrow) * cHM + k0]);
            bf16x8 a2 = *reinterpret_cast<const bf16x8*>(&w2b[(size_t)(mbase + 32 + lrow) * cHM + k0]);
#pragma unroll
            for (int nt = 0; nt < 4; nt++) {
                bf16x8 bf = *reinterpret_cast<const bf16x8*>(&hT[nt * 16 + lrow][k0]);
                acc[0][nt] = __builtin_amdgcn_mfma_f32_16x16x32_bf16(a0, bf, acc[0][nt], 0, 0, 0);
                acc[1][nt] = __builtin_amdgcn_mfma_f32_16x16x32_bf16(a1, bf, acc[1][nt], 0, 0, 0);
                acc[2][nt] = __builtin_amdgcn_mfma_f32_16x16x32_bf16(a2, bf, acc[2][nt], 0, 0, 0);
            }
        }
        float s = 0.f, q = 0.f;
#pragma unroll
        for (int mt = 0; mt < 3; mt++) {
#pragma unroll
            for (int nt = 0; nt < 4; nt++) {
#pragma unroll
                for (int r = 0; r < 4; r++) {
                    int o = mbase + mt * 16 + r0 + r;
                    int t = t0 + nt * 16 + lrow;
                    size_t idx = ((size_t)b * cH + o) * cT + t;
                    float val = z[idx] + acc[mt][nt][r];
                    z[idx] = val;
                    s += val; q += val * val;
                }
            }
        }
#pragma unroll
        for (int off = 32; off > 0; off >>= 1) { s += __shfl_down(s, off); q += __shfl_down(q, off); }
        if (lane == 0) {
            atomicAdd(&sums_out[b * 2], s);
            atomicAdd(&sums_out[b * 2 + 1], q);
        }
    }
}

// ---------------- global average pool ----------------
__global__ __launch_bounds__(256) void k_pool(const float* __restrict__ z,
                                              float* __restrict__ pooled) {
    int bh = blockIdx.x;
    const float* zp = z + (size_t)bh * cT;
    float s = 0.f;
    for (int t = threadIdx.x; t < cT; t += 256) s += zp[t];
    __shared__ float red[256];
    red[threadIdx.x] = s;
    __syncthreads();
    for (int st = 128; st > 0; st >>= 1) {
        if (threadIdx.x < st) red[threadIdx.x] += red[threadIdx.x + st];
        __syncthreads();
    }
    if (threadIdx.x == 0) pooled[bh] = red[0] * (1.0f / cT);
}

// ---------------- head ----------------
__global__ __launch_bounds__(256) void k_head(const float* __restrict__ pooled,
                                              const float* __restrict__ hw,
                                              const float* __restrict__ hb,
                                              float* __restrict__ out) {
    int i = blockIdx.x * 256 + threadIdx.x;
    if (i >= cB * cNCLS) return;
    int b = i / cNCLS, n = i % cNCLS;
    float acc = hb[n];
    const float* pw = pooled + b * cH;
    const float* wr = hw + n * cH;
    for (int h = 0; h < cH; h++) acc += pw[h] * wr[h];
    out[i] = acc;
}

extern "C" void kernel_launch(void* const* d_in, const int* in_sizes, int n_in,
                              void* d_out, int out_size, void* d_ws, size_t ws_size,
                              hipStream_t stream) {
    const float* x          = (const float*)d_in[0];
    const float* stem_w     = (const float*)d_in[1];
    const float* stem_bn_g  = (const float*)d_in[2];
    const float* stem_bn_b  = (const float*)d_in[3];
    const float* ln_g       = (const float*)d_in[4];
    const float* ln_b       = (const float*)d_in[5];
    const float* proj_w     = (const float*)d_in[6];
    const float* prototypes = (const float*)d_in[7];
    const float* route_lib  = (const float*)d_in[8];
    const float* gain_lib   = (const float*)d_in[9];
    const float* norm1_g    = (const float*)d_in[10];
    const float* norm1_b    = (const float*)d_in[11];
    const float* expert_w   = (const float*)d_in[12];
    const float* mix_w      = (const float*)d_in[13];
    const float* mix_bn_g   = (const float*)d_in[14];
    const float* mix_bn_b   = (const float*)d_in[15];
    const float* norm2_g    = (const float*)d_in[16];
    const float* norm2_b    = (const float*)d_in[17];
    const float* mlp_w1     = (const float*)d_in[18];
    const float* mlp_b1     = (const float*)d_in[19];
    const float* mlp_w2     = (const float*)d_in[20];
    const float* mlp_b2     = (const float*)d_in[21];
    const float* head_w     = (const float*)d_in[22];
    const float* head_b     = (const float*)d_in[23];

    float* ws = (float*)d_ws;
    size_t off = 0;
    const size_t ZN = (size_t)cB * cH * cT;
    float* zA      = ws + off; off += ZN;
    float* zB      = ws + off; off += ZN;
    float* mag     = ws + off; off += (size_t)cB * cBINS;      // 65568
    float* sums    = ws + off; off += 9 * cB * 2;              // 576 (zeroed with mag)
    float* basis   = ws + off; off += (size_t)cBANDS * cBINS;
    float* summary = ws + off; off += cB * cBANDS;
    float* routes  = ws + off; off += cB * cD * cE;
    float* gains   = ws + off; off += (size_t)cB * cD * cH;
    float* pooled  = ws + off; off += cB * cH;
    float2* tw     = (float2*)(ws + off); off += 2 * (cT - 1) + 2;
    unsigned short* mixb = (unsigned short*)(ws + off); off += (size_t)cD * cH * cH / 2;
    unsigned short* w1b  = (unsigned short*)(ws + off); off += (size_t)cD * cHM * cH / 2;
    unsigned short* w2b  = (unsigned short*)(ws + off); off += (size_t)cD * cH * cHM / 2;

    // zero atomic accumulators (mag + sums contiguous)
    int nz = cB * cBINS + 9 * cB * 2;
    k_zero<<<(nz + 255) / 256, 256, 0, stream>>>(mag, nz);

    // weight conversion to bf16
    k_cvt<<<(cD * cH * cH + 255) / 256, 256, 0, stream>>>(mix_w, mixb, cD * cH * cH);
    k_cvt<<<(cD * cHM * cH + 255) / 256, 256, 0, stream>>>(mlp_w1, w1b, cD * cHM * cH);
    k_cvt<<<(cD * cH * cHM + 255) / 256, 256, 0, stream>>>(mlp_w2, w2b, cD * cH * cHM);

    // spectral summary + router
    k_twiddle<<<12, 256, 0, stream>>>(tw);
    k_fft_mag<<<cB * cCIN, 256, 0, stream>>>(x, tw, mag);
    k_basis<<<cBANDS, 256, 0, stream>>>(basis);
    k_summary<<<cB, 256, 0, stream>>>(mag, basis, summary);
    k_router<<<1, 64, 0, stream>>>(summary, ln_g, ln_b, proj_w, prototypes,
                                   route_lib, gain_lib, routes, gains);

    // stem (+ stats for depth-0 GN1)
    k_stem<<<cB * (cT / STT), 256, 0, stream>>>(x, stem_w, stem_bn_g, stem_bn_b, zA,
                                                sums + 0 * cB * 2);

    // routed temporal blocks (ping-pong zA/zB)
    float* zi = zA;
    float* zo = zB;
    for (int d = 0; d < cD; d++) {
        k_block1<<<cB * (cT / TT), 256, 0, stream>>>(
            zi, zo, sums + (size_t)(2 * d) * cB * 2, sums + (size_t)(2 * d + 1) * cB * 2,
            norm1_g + d * cH, norm1_b + d * cH,
            expert_w + (size_t)d * cE * cH * cK, mixb + (size_t)d * cH * cH,
            mix_bn_g + d * cH, mix_bn_b + d * cH, routes, gains, d);
        k_block2<<<cB * (cT / TT), 256, 0, stream>>>(
            zo, sums + (size_t)(2 * d + 1) * cB * 2, sums + (size_t)(2 * d + 2) * cB * 2,
            norm2_g + d * cH, norm2_b + d * cH,
            w1b + (size_t)d * cHM * cH, mlp_b1 + d * cHM,
            w2b + (size_t)d * cH * cHM, mlp_b2 + d * cH);
        float* t = zi; zi = zo; zo = t;
    }

    // head
    k_pool<<<cB * cH, 256, 0, stream>>>(zi, pooled);
    k_head<<<(cB * cNCLS + 255) / 256, 256, 0, stream>>>(pooled, head_w, head_b,
                                                         (float*)d_out);
}